// Round 6
// baseline (8423.473 us; speedup 1.0000x reference)
//
#include <hip/hip_runtime.h>
#include <cstdint>
#include <cstddef>

#define SEQT  512
#define HID   1024
#define G3    3072

typedef __attribute__((ext_vector_type(8))) short bf16x8;
typedef __attribute__((ext_vector_type(8))) unsigned short u16x8;
typedef __attribute__((ext_vector_type(4))) float f32x4;

__device__ __forceinline__ float sigm(float x){ return 1.0f/(1.0f+expf(-x)); }
__device__ __forceinline__ float b2f(unsigned short s){ return __uint_as_float(((uint32_t)s)<<16); }
__device__ __forceinline__ unsigned short f2b(float f){
    uint32_t u=__float_as_uint(f);
    return (unsigned short)((u + 0x7FFFu + ((u>>16)&1u))>>16);
}

// ---------------------------------------------------------------------------
// MFMA GEMM: C[m][n] = epilogue( sum_k A[m][k]*W[n][k] )   (unchanged, proven)
// ---------------------------------------------------------------------------
template<int ASRC, int BSRC, int MODE>
__global__ __launch_bounds__(256) void mfma_gemm(
    const void* __restrict__ Av, const void* __restrict__ Bv,
    const float* __restrict__ bias, const float* __restrict__ ctx,
    const float* __restrict__ gate, void* __restrict__ Cv,
    int N, int K)
{
    __shared__ __align__(16) unsigned short As[128*64];
    __shared__ __align__(16) unsigned short Bs[128*64];
    const int tid = threadIdx.x;
    const int lane = tid & 63;
    const int w = tid >> 6;
    const int wm = w & 1, wn = w >> 1;
    const int m0 = blockIdx.y * 128, n0 = blockIdx.x * 128;

    f32x4 acc[4][4];
#pragma unroll
    for (int i = 0; i < 4; i++)
#pragma unroll
        for (int j = 0; j < 4; j++) acc[i][j] = (f32x4){0.f,0.f,0.f,0.f};

    for (int kt = 0; kt < K; kt += 64) {
        __syncthreads();
        if (ASRC == 0) {
            const unsigned short* Ab = (const unsigned short*)Av;
#pragma unroll
            for (int c = 0; c < 4; c++) {
                const int chunk = w*4 + c;
                const int row = chunk*8 + (lane>>3);
                const unsigned short* src = Ab + (size_t)(m0+row)*K + kt + (lane&7)*8;
                __builtin_amdgcn_global_load_lds(
                    (const __attribute__((address_space(1))) void*)src,
                    (__attribute__((address_space(3))) void*)&As[chunk*512], 16, 0, 0);
            }
        } else if (ASRC == 1) {
            const float* Af = (const float*)Av;
#pragma unroll
            for (int p = 0; p < 4; p++) {
                const int q = p*256 + tid, row = q>>3, kc = q&7;
                const float* src = Af + (size_t)(m0+row)*K + kt + kc*8;
                float4 u = *(const float4*)src, v = *(const float4*)(src+4);
                __align__(16) unsigned short tmp[8] =
                    {f2b(u.x),f2b(u.y),f2b(u.z),f2b(u.w),f2b(v.x),f2b(v.y),f2b(v.z),f2b(v.w)};
                *(bf16x8*)&As[row*64 + kc*8] = *(const bf16x8*)tmp;
            }
        } else {
            const unsigned short* Ab = (const unsigned short*)Av;
#pragma unroll
            for (int p = 0; p < 4; p++) {
                const int q = p*256 + tid, row = q>>3, kc = q&7;
                const int b = (m0+row) >> 9;
                u16x8 hv = *(const u16x8*)(Ab + (size_t)(m0+row)*K + kt + kc*8);
                const float* gp = gate + (size_t)b*HID + kt + kc*8;
                float4 g0 = *(const float4*)gp, g1 = *(const float4*)(gp+4);
                const float gg[8] = {g0.x,g0.y,g0.z,g0.w,g1.x,g1.y,g1.z,g1.w};
                __align__(16) unsigned short tmp[8];
#pragma unroll
                for (int e = 0; e < 8; e++)
                    tmp[e] = f2b(b2f(hv[e]) * (1.0f + gg[e]));
                *(bf16x8*)&As[row*64 + kc*8] = *(const bf16x8*)tmp;
            }
        }
        if (BSRC == 0) {
            const unsigned short* Bb = (const unsigned short*)Bv;
#pragma unroll
            for (int c = 0; c < 4; c++) {
                const int chunk = w*4 + c;
                const int row = chunk*8 + (lane>>3);
                const unsigned short* src = Bb + (size_t)(n0+row)*K + kt + (lane&7)*8;
                __builtin_amdgcn_global_load_lds(
                    (const __attribute__((address_space(1))) void*)src,
                    (__attribute__((address_space(3))) void*)&Bs[chunk*512], 16, 0, 0);
            }
        } else {
            const float* Bf = (const float*)Bv;
#pragma unroll
            for (int p = 0; p < 4; p++) {
                const int q = p*256 + tid, row = q>>3, kc = q&7;
                const float* src = Bf + (size_t)(n0+row)*K + kt + kc*8;
                float4 u = *(const float4*)src, v = *(const float4*)(src+4);
                __align__(16) unsigned short tmp[8] =
                    {f2b(u.x),f2b(u.y),f2b(u.z),f2b(u.w),f2b(v.x),f2b(v.y),f2b(v.z),f2b(v.w)};
                *(bf16x8*)&Bs[row*64 + kc*8] = *(const bf16x8*)tmp;
            }
        }
        __syncthreads();
#pragma unroll
        for (int kg = 0; kg < 2; kg++) {
            bf16x8 af[4], bfr[4];
#pragma unroll
            for (int mi = 0; mi < 4; mi++)
                af[mi] = *(const bf16x8*)&As[(wm*64+mi*16+(lane&15))*64 + kg*32 + (lane>>4)*8];
#pragma unroll
            for (int ni = 0; ni < 4; ni++)
                bfr[ni] = *(const bf16x8*)&Bs[(wn*64+ni*16+(lane&15))*64 + kg*32 + (lane>>4)*8];
#pragma unroll
            for (int mi = 0; mi < 4; mi++)
#pragma unroll
                for (int ni = 0; ni < 4; ni++)
                    acc[mi][ni] = __builtin_amdgcn_mfma_f32_16x16x32_bf16(
                        af[mi], bfr[ni], acc[mi][ni], 0, 0, 0);
        }
    }

    const int cl = lane & 15, rg = lane >> 4;
    const int bct = m0 >> 9;
#pragma unroll
    for (int mi = 0; mi < 4; mi++) {
        const int rowb = m0 + wm*64 + mi*16 + rg*4;
#pragma unroll
        for (int ni = 0; ni < 4; ni++) {
            const int col = n0 + wn*64 + ni*16 + cl;
            const float bv = bias[col];
            const float cv = (MODE==1) ? ctx[(size_t)bct*HID + col] : 0.0f;
#pragma unroll
            for (int r = 0; r < 4; r++) {
                float val = acc[mi][ni][r] + bv;
                if (MODE==1) val = tanhf(val + cv);
                const size_t off = (size_t)(rowb+r)*N + col;
                if (MODE==0) ((float*)Cv)[off] = val;
                else ((unsigned short*)Cv)[off] = f2b(val);
            }
        }
    }
}

// ---------------------------------------------------------------------------
__global__ __launch_bounds__(256) void gate_kernel(
    const float* __restrict__ ctx, const float* __restrict__ Wg,
    const float* __restrict__ bg, float* __restrict__ gate)
{
    const int j = blockIdx.x * 256 + threadIdx.x;
    const int b = blockIdx.y;
    const float4* cp = (const float4*)(ctx + (size_t)b * HID);
    const float4* wp = (const float4*)(Wg + (size_t)j * HID);
    float acc = 0.0f;
#pragma unroll 4
    for (int k = 0; k < HID / 4; k++) {
        float4 c = cp[k], w = wp[k];
        acc += c.x * w.x + c.y * w.y + c.z * w.z + c.w * w.w;
    }
    gate[(size_t)b * HID + j] = sigm(acc + bg[j]);
}

// ---------------------------------------------------------------------------
__global__ __launch_bounds__(256) void f2b_kernel(
    const float* __restrict__ in, unsigned short* __restrict__ out, int n)
{
    const int i = (blockIdx.x * 256 + threadIdx.x) * 4;
    if (i < n) {
        float4 v = *(const float4*)(in + i);
        unsigned short s[4] = {f2b(v.x), f2b(v.y), f2b(v.z), f2b(v.w)};
        *(short4*)(out + i) = *(short4*)s;
    }
}

// ---------------------------------------------------------------------------
// Persistent GRU layer scan v3.
//  * depth-16 register-pipelined h loads (hb[16], refill during 1st half MFMA)
//  * finalize -> hlds staging; wave 5 alone publishes (wide agent stores +
//    vmcnt(0) + flag) while waves 0-4 loop ahead to xg-issue + poll.
// 64 blocks x 384 thr. Block owns 16 j-columns; Whh slice bf16 in LDS.
// ---------------------------------------------------------------------------
__global__ __launch_bounds__(384, 1) void gru_scan(
    const float* __restrict__ Whh, const float* __restrict__ bhh,
    const unsigned short* __restrict__ xg, unsigned short* __restrict__ hbuf,
    unsigned int* __restrict__ flags)
{
    __shared__ __align__(16) unsigned short wlds[48*1032];
    __shared__ float sc[3][32][17];
    __shared__ uint32_t hlds[32][8];
    const int tid = threadIdx.x;
    const int lane = tid & 63;
    const int w = tid >> 6;
    const int bid = blockIdx.x;
    const int j0 = bid * 16;
    const int mh = w & 1, g = w >> 1;
    const int cl = lane & 15, kq = lane >> 4;

    // stage Whh slice f32 -> bf16 LDS: row rr=g*16+jr <- Whh[g*1024 + j0+jr]
    for (int i = tid; i < 48*128; i += 384) {
        const int rr = i >> 7, kc = i & 127;
        const int grow = (rr>>4)*1024 + j0 + (rr&15);
        const float* src = Whh + (size_t)grow*1024 + kc*8;
        float4 u = *(const float4*)src, v = *(const float4*)(src+4);
        __align__(16) unsigned short tmp[8] =
            {f2b(u.x),f2b(u.y),f2b(u.z),f2b(u.w),f2b(v.x),f2b(v.y),f2b(v.z),f2b(v.w)};
        *(bf16x8*)&wlds[rr*1032 + kc*8] = *(const bf16x8*)tmp;
    }
    __syncthreads();

    const unsigned short* wrow = &wlds[(g*16+cl)*1032 + kq*8];

    // finalize-thread identity (tid<256): batch fb, column pair j0+fj
    const int fb = tid >> 3;
    const int fj = (tid & 7) * 2;
    float hp0 = 0.f, hp1 = 0.f;
    float br0=0,br1=0,bz0=0,bz1=0,bn0=0,bn1=0;
    if (tid < 256) {
        br0 = bhh[j0+fj];          br1 = bhh[j0+fj+1];
        bz0 = bhh[HID+j0+fj];      bz1 = bhh[HID+j0+fj+1];
        bn0 = bhh[2*HID+j0+fj];    bn1 = bhh[2*HID+j0+fj+1];
    }

    for (int t = 0; t < SEQT; t++) {
        // issue xg[t] loads before the wait (HBM latency hides under poll)
        uint32_t xr2=0, xz2=0, xn2=0;
        if (tid < 256) {
            const unsigned short* xp = xg + ((size_t)fb*SEQT + t)*G3 + j0 + fj;
            xr2 = *(const uint32_t*)(xp);
            xz2 = *(const uint32_t*)(xp + 1024);
            xn2 = *(const uint32_t*)(xp + 2048);
        }

        // wait until every block has published h[t-1]
        if (t > 0) {
            if (w == 0) {
                const unsigned int tgt = (unsigned int)t;
                while (__hip_atomic_load(&flags[lane*16], __ATOMIC_RELAXED,
                                         __HIP_MEMORY_SCOPE_AGENT) < tgt) {}
            }
            __syncthreads();
        }

        f32x4 a[4];
#pragma unroll
        for (int i = 0; i < 4; i++) a[i] = (f32x4){0.f,0.f,0.f,0.f};

        if (t > 0) {
            const unsigned short* hrow =
                hbuf + ((size_t)(mh*16+cl)*SEQT + (t-1))*HID + kq*8;
            bf16x8 hb[16];
            // pre-issue 16 h loads (depth-16 pipeline, ~128 VGPRs)
#pragma unroll
            for (int i = 0; i < 16; i++)
                hb[i] = *(const bf16x8*)(hrow + (size_t)i*32);
            // first half: consume hb[i], refill with load (16+i)
#pragma unroll
            for (int i = 0; i < 16; i++) {
                bf16x8 wv = *(const bf16x8*)(wrow + (size_t)i*32);
                bf16x8 hv = hb[i];
                hb[i] = *(const bf16x8*)(hrow + (size_t)(16+i)*32);
                a[i&3] = __builtin_amdgcn_mfma_f32_16x16x32_bf16(hv, wv, a[i&3], 0,0,0);
            }
            // second half
#pragma unroll
            for (int i = 0; i < 16; i++) {
                bf16x8 wv = *(const bf16x8*)(wrow + (size_t)(16+i)*32);
                a[i&3] = __builtin_amdgcn_mfma_f32_16x16x32_bf16(hb[i], wv, a[i&3], 0,0,0);
            }
        }
        f32x4 av = (a[0] + a[1]) + (a[2] + a[3]);
#pragma unroll
        for (int r = 0; r < 4; r++)
            sc[g][mh*16 + kq*4 + r][cl] = av[r];
        __syncthreads();

        if (tid < 256) {
            const float r0 = sigm(b2f((unsigned short)(xr2 & 0xFFFF))      + sc[0][fb][fj]   + br0);
            const float r1 = sigm(b2f((unsigned short)(xr2 >> 16))         + sc[0][fb][fj+1] + br1);
            const float z0 = sigm(b2f((unsigned short)(xz2 & 0xFFFF))      + sc[1][fb][fj]   + bz0);
            const float z1 = sigm(b2f((unsigned short)(xz2 >> 16))         + sc[1][fb][fj+1] + bz1);
            const float n0 = tanhf(b2f((unsigned short)(xn2 & 0xFFFF)) + r0*(sc[2][fb][fj]   + bn0));
            const float n1 = tanhf(b2f((unsigned short)(xn2 >> 16))    + r1*(sc[2][fb][fj+1] + bn1));
            const float h0 = (1.0f - z0)*n0 + z0*hp0;
            const float h1 = (1.0f - z1)*n1 + z1*hp1;
            hp0 = h0; hp1 = h1;
            hlds[fb][fj >> 1] = (uint32_t)f2b(h0) | ((uint32_t)f2b(h1) << 16);
        }
        __syncthreads();

        // wave 5 publishes; waves 0-4 loop ahead to xg-issue + poll for t+1
        if (w == 5) {
            const int pb = lane >> 1, ph = lane & 1;   // batch, 8-short half
            const uint32_t v0 = hlds[pb][ph*4 + 0];
            const uint32_t v1 = hlds[pb][ph*4 + 1];
            const uint32_t v2 = hlds[pb][ph*4 + 2];
            const uint32_t v3 = hlds[pb][ph*4 + 3];
            uint64_t* dst = (uint64_t*)(hbuf + ((size_t)pb*SEQT + t)*HID + j0 + ph*8);
            __hip_atomic_store(dst,   (uint64_t)v0 | ((uint64_t)v1 << 32),
                               __ATOMIC_RELAXED, __HIP_MEMORY_SCOPE_AGENT);
            __hip_atomic_store(dst+1, (uint64_t)v2 | ((uint64_t)v3 << 32),
                               __ATOMIC_RELAXED, __HIP_MEMORY_SCOPE_AGENT);
            asm volatile("s_waitcnt vmcnt(0)" ::: "memory");
            if (lane == 0)
                __hip_atomic_store(&flags[bid*16], (unsigned int)(t+1),
                                   __ATOMIC_RELAXED, __HIP_MEMORY_SCOPE_AGENT);
        }
    }
}

// ---------------------------------------------------------------------------
__global__ __launch_bounds__(256) void diag_kernel(float* __restrict__ out,
                                                   int n, float code)
{
    for (int i = blockIdx.x * 256 + threadIdx.x; i < n; i += gridDim.x * 256)
        out[i] = (i == 0) ? code : 0.0f;
}

// ---------------------------------------------------------------------------
extern "C" void kernel_launch(void* const* d_in, const int* in_sizes, int n_in,
                              void* d_out, int out_size, void* d_ws, size_t ws_size,
                              hipStream_t stream)
{
    const float* x      = (const float*)d_in[0];
    const float* ctx    = (const float*)d_in[1];
    const float* W_in   = (const float*)d_in[2];
    const float* b_in   = (const float*)d_in[3];
    const float* Wih0   = (const float*)d_in[4];
    const float* Whh0   = (const float*)d_in[5];
    const float* bih0   = (const float*)d_in[6];
    const float* bhh0   = (const float*)d_in[7];
    const float* Wih1   = (const float*)d_in[8];
    const float* Whh1   = (const float*)d_in[9];
    const float* bih1   = (const float*)d_in[10];
    const float* bhh1   = (const float*)d_in[11];
    const float* W_out  = (const float*)d_in[12];
    const float* b_out  = (const float*)d_in[13];
    const float* W_gate = (const float*)d_in[14];
    const float* b_gate = (const float*)d_in[15];
    float* out = (float*)d_out;

    const size_t XG  = (size_t)16384 * 3072 * 2;
    const size_t HB  = (size_t)16384 * 1024 * 2;
    const size_t WB  = (size_t)3072 * 1024 * 2;
    const size_t GT  = (size_t)32 * 1024 * 4;
    const size_t need = XG + HB + 2*WB + GT + 16384;

    if (ws_size < need) {
        diag_kernel<<<2048, 256, 0, stream>>>(out, out_size, (float)(ws_size >> 20));
        return;
    }

    char* ws = (char*)d_ws;
    unsigned short* xgb   = (unsigned short*)ws;
    unsigned short* hbuf  = (unsigned short*)(ws + XG);
    unsigned short* wih0b = (unsigned short*)(ws + XG + HB);
    unsigned short* wih1b = (unsigned short*)(ws + XG + HB + WB);
    float*          gate  = (float*)(ws + XG + HB + 2*WB);
    unsigned int*   flags = (unsigned int*)(ws + XG + HB + 2*WB + GT);

    f2b_kernel<<<3072, 256, 0, stream>>>(Wih0, wih0b, 3072 * 1024);
    f2b_kernel<<<3072, 256, 0, stream>>>(Wih1, wih1b, 3072 * 1024);
    gate_kernel<<<dim3(4, 32), 256, 0, stream>>>(ctx, W_gate, b_gate, gate);
    hipMemsetAsync(flags, 0, 16384, stream);

    // mixed = tanh(x @ W_in^T + b_in + ctx[b]) -> hbuf (bf16)
    mfma_gemm<1, 1, 1><<<dim3(8, 128), 256, 0, stream>>>(
        x, W_in, b_in, ctx, nullptr, hbuf, 1024, 1024);

    // xg0 = mixed @ Wih0^T + bih0 -> xgb
    mfma_gemm<0, 0, 2><<<dim3(24, 128), 256, 0, stream>>>(
        hbuf, wih0b, bih0, nullptr, nullptr, xgb, 3072, 1024);

    // GRU layer 0 persistent scan (h1 overwrites hbuf)
    gru_scan<<<64, 384, 0, stream>>>(Whh0, bhh0, xgb, hbuf, flags);

    // xg1 = h1 @ Wih1^T + bih1 -> xgb
    mfma_gemm<0, 0, 2><<<dim3(24, 128), 256, 0, stream>>>(
        hbuf, wih1b, bih1, nullptr, nullptr, xgb, 3072, 1024);

    // GRU layer 1 persistent scan (h2 overwrites hbuf)
    gru_scan<<<64, 384, 0, stream>>>(Whh1, bhh1, xgb, hbuf, flags + 2048);

    // out = (h2 * (1+gate)) @ W_out^T + b_out -> f32
    mfma_gemm<2, 1, 0><<<dim3(8, 128), 256, 0, stream>>>(
        hbuf, W_out, b_out, nullptr, gate, out, 1024, 1024);
}

// Round 7
// 4458.783 us; speedup vs baseline: 1.8892x; 1.8892x over previous
//
#include <hip/hip_runtime.h>
#include <cstdint>
#include <cstddef>

#define SEQT  512
#define HID   1024
#define G3    3072

typedef __attribute__((ext_vector_type(8))) short bf16x8;
typedef __attribute__((ext_vector_type(8))) unsigned short u16x8;
typedef __attribute__((ext_vector_type(4))) float f32x4;

__device__ __forceinline__ float sigm(float x){ return 1.0f/(1.0f+expf(-x)); }
__device__ __forceinline__ float b2f(unsigned short s){ return __uint_as_float(((uint32_t)s)<<16); }
__device__ __forceinline__ unsigned short f2b(float f){
    uint32_t u=__float_as_uint(f);
    return (unsigned short)((u + 0x7FFFu + ((u>>16)&1u))>>16);
}

// ---------------------------------------------------------------------------
// MFMA GEMM (proven since R3). ASRC: 1=f32 reg-staged, 2=bf16 + (1+gate) fuse.
// BSRC: 1=f32 reg-staged. MODE: 0=f32+bias, 1=bf16 tanh(+bias+ctx).
// ---------------------------------------------------------------------------
template<int ASRC, int BSRC, int MODE>
__global__ __launch_bounds__(256) void mfma_gemm(
    const void* __restrict__ Av, const void* __restrict__ Bv,
    const float* __restrict__ bias, const float* __restrict__ ctx,
    const float* __restrict__ gate, void* __restrict__ Cv,
    int N, int K)
{
    __shared__ __align__(16) unsigned short As[128*64];
    __shared__ __align__(16) unsigned short Bs[128*64];
    const int tid = threadIdx.x;
    const int lane = tid & 63;
    const int w = tid >> 6;
    const int wm = w & 1, wn = w >> 1;
    const int m0 = blockIdx.y * 128, n0 = blockIdx.x * 128;

    f32x4 acc[4][4];
#pragma unroll
    for (int i = 0; i < 4; i++)
#pragma unroll
        for (int j = 0; j < 4; j++) acc[i][j] = (f32x4){0.f,0.f,0.f,0.f};

    for (int kt = 0; kt < K; kt += 64) {
        __syncthreads();
        if (ASRC == 1) {
            const float* Af = (const float*)Av;
#pragma unroll
            for (int p = 0; p < 4; p++) {
                const int q = p*256 + tid, row = q>>3, kc = q&7;
                const float* src = Af + (size_t)(m0+row)*K + kt + kc*8;
                float4 u = *(const float4*)src, v = *(const float4*)(src+4);
                __align__(16) unsigned short tmp[8] =
                    {f2b(u.x),f2b(u.y),f2b(u.z),f2b(u.w),f2b(v.x),f2b(v.y),f2b(v.z),f2b(v.w)};
                *(bf16x8*)&As[row*64 + kc*8] = *(const bf16x8*)tmp;
            }
        } else {
            const unsigned short* Ab = (const unsigned short*)Av;
#pragma unroll
            for (int p = 0; p < 4; p++) {
                const int q = p*256 + tid, row = q>>3, kc = q&7;
                const int b = (m0+row) >> 9;
                u16x8 hv = *(const u16x8*)(Ab + (size_t)(m0+row)*K + kt + kc*8);
                const float* gp = gate + (size_t)b*HID + kt + kc*8;
                float4 g0 = *(const float4*)gp, g1 = *(const float4*)(gp+4);
                const float gg[8] = {g0.x,g0.y,g0.z,g0.w,g1.x,g1.y,g1.z,g1.w};
                __align__(16) unsigned short tmp[8];
#pragma unroll
                for (int e = 0; e < 8; e++)
                    tmp[e] = f2b(b2f(hv[e]) * (1.0f + gg[e]));
                *(bf16x8*)&As[row*64 + kc*8] = *(const bf16x8*)tmp;
            }
        }
        {
            const float* Bf = (const float*)Bv;
#pragma unroll
            for (int p = 0; p < 4; p++) {
                const int q = p*256 + tid, row = q>>3, kc = q&7;
                const float* src = Bf + (size_t)(n0+row)*K + kt + kc*8;
                float4 u = *(const float4*)src, v = *(const float4*)(src+4);
                __align__(16) unsigned short tmp[8] =
                    {f2b(u.x),f2b(u.y),f2b(u.z),f2b(u.w),f2b(v.x),f2b(v.y),f2b(v.z),f2b(v.w)};
                *(bf16x8*)&Bs[row*64 + kc*8] = *(const bf16x8*)tmp;
            }
        }
        __syncthreads();
#pragma unroll
        for (int kg = 0; kg < 2; kg++) {
            bf16x8 af[4], bfr[4];
#pragma unroll
            for (int mi = 0; mi < 4; mi++)
                af[mi] = *(const bf16x8*)&As[(wm*64+mi*16+(lane&15))*64 + kg*32 + (lane>>4)*8];
#pragma unroll
            for (int ni = 0; ni < 4; ni++)
                bfr[ni] = *(const bf16x8*)&Bs[(wn*64+ni*16+(lane&15))*64 + kg*32 + (lane>>4)*8];
#pragma unroll
            for (int mi = 0; mi < 4; mi++)
#pragma unroll
                for (int ni = 0; ni < 4; ni++)
                    acc[mi][ni] = __builtin_amdgcn_mfma_f32_16x16x32_bf16(
                        af[mi], bfr[ni], acc[mi][ni], 0, 0, 0);
        }
    }

    const int cl = lane & 15, rg = lane >> 4;
    const int bct = m0 >> 9;
#pragma unroll
    for (int mi = 0; mi < 4; mi++) {
        const int rowb = m0 + wm*64 + mi*16 + rg*4;
#pragma unroll
        for (int ni = 0; ni < 4; ni++) {
            const int col = n0 + wn*64 + ni*16 + cl;
            const float bv = bias[col];
            const float cv = (MODE==1) ? ctx[(size_t)bct*HID + col] : 0.0f;
#pragma unroll
            for (int r = 0; r < 4; r++) {
                float val = acc[mi][ni][r] + bv;
                if (MODE==1) val = tanhf(val + cv);
                const size_t off = (size_t)(rowb+r)*N + col;
                if (MODE==0) ((float*)Cv)[off] = val;
                else ((unsigned short*)Cv)[off] = f2b(val);
            }
        }
    }
}

// ---------------------------------------------------------------------------
__global__ __launch_bounds__(256) void gate_kernel(
    const float* __restrict__ ctx, const float* __restrict__ Wg,
    const float* __restrict__ bg, float* __restrict__ gate)
{
    const int j = blockIdx.x * 256 + threadIdx.x;
    const int b = blockIdx.y;
    const float4* cp = (const float4*)(ctx + (size_t)b * HID);
    const float4* wp = (const float4*)(Wg + (size_t)j * HID);
    float acc = 0.0f;
#pragma unroll 4
    for (int k = 0; k < HID / 4; k++) {
        float4 c = cp[k], w = wp[k];
        acc += c.x * w.x + c.y * w.y + c.z * w.z + c.w * w.w;
    }
    gate[(size_t)b * HID + j] = sigm(acc + bg[j]);
}

// ---------------------------------------------------------------------------
// 4-stage pipelined GRU section, one dispatch, 256 blocks x 384 threads.
// role = bid>>6:  0=P0 (xg0=Wih0@mixed)  1=R0 (h1 recurrence)
//                 2=P1 (xg1=Wih1@h1)     3=R1 (h2 recurrence)
// Producers write bf16 gate-sums into an 8-deep ring xgs[rb][slot][32][48]
// (agent stores); recurrents read them with agent-scope ATOMIC u32 loads
// (L2-bypassing -> ring reuse is stale-safe). h1/h2 are full series (each
// address written once, read once -> plain loads safe). Flags (64B-strided):
//   fP0 | fR0 | fP1 | fR1. Back-pressure: P waits its consumer R >= t-7.
// ---------------------------------------------------------------------------
__device__ __forceinline__ void matvec32(const unsigned short* hrow,
                                         const unsigned short* wrow,
                                         f32x4& A0, f32x4& A1, f32x4& A2, f32x4& A3)
{
#pragma unroll
    for (int kg = 0; kg < 32; kg += 4) {
        bf16x8 h0 = *(const bf16x8*)(hrow + (size_t)(kg+0)*32);
        bf16x8 w0 = *(const bf16x8*)(wrow + (size_t)(kg+0)*32);
        A0 = __builtin_amdgcn_mfma_f32_16x16x32_bf16(h0, w0, A0, 0,0,0);
        bf16x8 h1 = *(const bf16x8*)(hrow + (size_t)(kg+1)*32);
        bf16x8 w1 = *(const bf16x8*)(wrow + (size_t)(kg+1)*32);
        A1 = __builtin_amdgcn_mfma_f32_16x16x32_bf16(h1, w1, A1, 0,0,0);
        bf16x8 h2 = *(const bf16x8*)(hrow + (size_t)(kg+2)*32);
        bf16x8 w2 = *(const bf16x8*)(wrow + (size_t)(kg+2)*32);
        A2 = __builtin_amdgcn_mfma_f32_16x16x32_bf16(h2, w2, A2, 0,0,0);
        bf16x8 h3 = *(const bf16x8*)(hrow + (size_t)(kg+3)*32);
        bf16x8 w3 = *(const bf16x8*)(wrow + (size_t)(kg+3)*32);
        A3 = __builtin_amdgcn_mfma_f32_16x16x32_bf16(h3, w3, A3, 0,0,0);
    }
}

__global__ __launch_bounds__(384, 1) void gru_pipe(
    const float* __restrict__ Wih0, const float* __restrict__ Whh0,
    const float* __restrict__ bih0, const float* __restrict__ bhh0,
    const float* __restrict__ Wih1, const float* __restrict__ Whh1,
    const float* __restrict__ bih1, const float* __restrict__ bhh1,
    const unsigned short* __restrict__ mixed,   // [B*T][H] bf16
    unsigned short* __restrict__ h1,            // [B*T... [b][t][H] bf16
    unsigned short* __restrict__ h2,
    unsigned short* __restrict__ xgs0,          // [64][8][32][48] bf16
    unsigned short* __restrict__ xgs1,
    unsigned int* __restrict__ flags)           // 4 sets x 64 x 16 u32
{
    __shared__ __align__(16) unsigned short wlds[48*1032];
    __shared__ float sc[3][32][17];
    __shared__ uint32_t hlds[32][8];
    const int tid = threadIdx.x;
    const int lane = tid & 63;
    const int w = tid >> 6;
    const int bid = blockIdx.x;
    const int role = bid >> 6, rb = bid & 63;
    const int j0 = rb * 16;
    const int mh = w & 1, g = w >> 1;
    const int cl = lane & 15, kq = lane >> 4;

    unsigned int* fset[4] = { flags, flags + 1024, flags + 2048, flags + 3072 };

    // stage this role's 48-row weight slice f32 -> bf16 LDS
    const float* Wsrc = (role == 0) ? Wih0 : (role == 1) ? Whh0
                      : (role == 2) ? Wih1 : Whh1;
    for (int i = tid; i < 48*128; i += 384) {
        const int rr = i >> 7, kc = i & 127;
        const int grow = (rr>>4)*1024 + j0 + (rr&15);
        const float* src = Wsrc + (size_t)grow*1024 + kc*8;
        float4 u = *(const float4*)src, v = *(const float4*)(src+4);
        __align__(16) unsigned short tmp[8] =
            {f2b(u.x),f2b(u.y),f2b(u.z),f2b(u.w),f2b(v.x),f2b(v.y),f2b(v.z),f2b(v.w)};
        *(bf16x8*)&wlds[rr*1032 + kc*8] = *(const bf16x8*)tmp;
    }
    __syncthreads();

    const unsigned short* wrow = &wlds[(g*16+cl)*1032 + kq*8];

    if ((role & 1) == 0) {
        // ---------------- producer: xg = Wih @ hsrc[t] -------------------
        const unsigned short* hsrc = (role == 0) ? mixed : h1;
        unsigned short* xgs = ((role == 0) ? xgs0 : xgs1) + (size_t)rb*8*32*48;
        const unsigned int* waitin = (role == 2) ? fset[1] : nullptr; // P1 waits R0
        const unsigned int* bp     = (role == 0) ? fset[1] : fset[3]; // consumer R
        unsigned int* myflag = &fset[role][rb*16];

        for (int t = 0; t < SEQT; t++) {
            if (w == 0 && waitin) {
                while (__hip_atomic_load(&waitin[lane*16], __ATOMIC_RELAXED,
                                         __HIP_MEMORY_SCOPE_AGENT) < (unsigned)(t+1)) {}
            }
            if (w == 1 && t >= 8) {
                while (__hip_atomic_load(&bp[lane*16], __ATOMIC_RELAXED,
                                         __HIP_MEMORY_SCOPE_AGENT) < (unsigned)(t-7)) {}
            }
            __syncthreads();

            f32x4 a0 = {0.f,0.f,0.f,0.f}, a1 = a0, a2 = a0, a3 = a0;
            const unsigned short* hrow =
                hsrc + ((size_t)(mh*16+cl)*SEQT + t)*HID + kq*8;
            matvec32(hrow, wrow, a0, a1, a2, a3);
            f32x4 av = (a0 + a1) + (a2 + a3);
#pragma unroll
            for (int r = 0; r < 4; r++)
                sc[g][mh*16 + kq*4 + r][cl] = av[r];
            __syncthreads();

            if (tid < 192) {
                const int b = tid / 6, c16 = (tid % 6) * 8;
                unsigned short v[8];
#pragma unroll
                for (int k = 0; k < 8; k++) {
                    const int col = c16 + k;
                    v[k] = f2b(sc[col >> 4][b][col & 15]);
                }
                const uint64_t lo = (uint64_t)v[0] | ((uint64_t)v[1]<<16)
                                  | ((uint64_t)v[2]<<32) | ((uint64_t)v[3]<<48);
                const uint64_t hi = (uint64_t)v[4] | ((uint64_t)v[5]<<16)
                                  | ((uint64_t)v[6]<<32) | ((uint64_t)v[7]<<48);
                uint64_t* dst = (uint64_t*)(xgs + (((size_t)(t&7)*32 + b)*48 + c16));
                __hip_atomic_store(dst,   lo, __ATOMIC_RELAXED, __HIP_MEMORY_SCOPE_AGENT);
                __hip_atomic_store(dst+1, hi, __ATOMIC_RELAXED, __HIP_MEMORY_SCOPE_AGENT);
            }
            asm volatile("s_waitcnt vmcnt(0)" ::: "memory");
            __syncthreads();
            if (tid == 0)
                __hip_atomic_store(myflag, (unsigned)(t+1),
                                   __ATOMIC_RELAXED, __HIP_MEMORY_SCOPE_AGENT);
        }
    } else {
        // ---------------- recurrent: h[t] from xgs[t] + Whh@h[t-1] -------
        const unsigned short* xgs = ((role == 1) ? xgs0 : xgs1) + (size_t)rb*8*32*48;
        unsigned short* hdst = (role == 1) ? h1 : h2;
        const float* bih = (role == 1) ? bih0 : bih1;
        const float* bhh = (role == 1) ? bhh0 : bhh1;
        const unsigned int* peers = fset[role];
        const unsigned int* prodf = &fset[role-1][rb*16];
        unsigned int* myflag = &fset[role][rb*16];

        const int fb = tid >> 3;
        const int fj = (tid & 7) * 2;
        float hp0 = 0.f, hp1 = 0.f;
        float br0=0,br1=0,bz0=0,bz1=0,bni0=0,bni1=0,bnh0=0,bnh1=0;
        if (tid < 256) {
            br0 = bih[j0+fj]        + bhh[j0+fj];
            br1 = bih[j0+fj+1]      + bhh[j0+fj+1];
            bz0 = bih[HID+j0+fj]    + bhh[HID+j0+fj];
            bz1 = bih[HID+j0+fj+1]  + bhh[HID+j0+fj+1];
            bni0 = bih[2*HID+j0+fj];   bni1 = bih[2*HID+j0+fj+1];
            bnh0 = bhh[2*HID+j0+fj];   bnh1 = bhh[2*HID+j0+fj+1];
        }

        for (int t = 0; t < SEQT; t++) {
            if (w == 0 && t > 0) {
                while (__hip_atomic_load(&peers[lane*16], __ATOMIC_RELAXED,
                                         __HIP_MEMORY_SCOPE_AGENT) < (unsigned)t) {}
            }
            if (w == 2 && lane == 0) {
                while (__hip_atomic_load(prodf, __ATOMIC_RELAXED,
                                         __HIP_MEMORY_SCOPE_AGENT) < (unsigned)(t+1)) {}
            }
            __syncthreads();

            // xg ring reads: agent-scope atomics (L2-bypass, stale-safe)
            uint32_t xr2=0, xz2=0, xn2=0;
            if (tid < 256) {
                const unsigned short* xp = xgs + ((size_t)(t&7)*32 + fb)*48;
                xr2 = __hip_atomic_load((const unsigned int*)(xp + fj),
                                        __ATOMIC_RELAXED, __HIP_MEMORY_SCOPE_AGENT);
                xz2 = __hip_atomic_load((const unsigned int*)(xp + 16 + fj),
                                        __ATOMIC_RELAXED, __HIP_MEMORY_SCOPE_AGENT);
                xn2 = __hip_atomic_load((const unsigned int*)(xp + 32 + fj),
                                        __ATOMIC_RELAXED, __HIP_MEMORY_SCOPE_AGENT);
            }

            f32x4 a0 = {0.f,0.f,0.f,0.f}, a1 = a0, a2 = a0, a3 = a0;
            if (t > 0) {
                const unsigned short* hrow =
                    hdst + ((size_t)(mh*16+cl)*SEQT + (t-1))*HID + kq*8;
                matvec32(hrow, wrow, a0, a1, a2, a3);
            }
            f32x4 av = (a0 + a1) + (a2 + a3);
#pragma unroll
            for (int r = 0; r < 4; r++)
                sc[g][mh*16 + kq*4 + r][cl] = av[r];
            __syncthreads();

            if (tid < 256) {
                const float r0 = sigm(b2f((unsigned short)(xr2 & 0xFFFF)) + sc[0][fb][fj]   + br0);
                const float r1 = sigm(b2f((unsigned short)(xr2 >> 16))    + sc[0][fb][fj+1] + br1);
                const float z0 = sigm(b2f((unsigned short)(xz2 & 0xFFFF)) + sc[1][fb][fj]   + bz0);
                const float z1 = sigm(b2f((unsigned short)(xz2 >> 16))    + sc[1][fb][fj+1] + bz1);
                const float n0 = tanhf(b2f((unsigned short)(xn2 & 0xFFFF)) + bni0
                                       + r0*(sc[2][fb][fj]   + bnh0));
                const float n1 = tanhf(b2f((unsigned short)(xn2 >> 16))    + bni1
                                       + r1*(sc[2][fb][fj+1] + bnh1));
                const float h0 = (1.0f - z0)*n0 + z0*hp0;
                const float h1v = (1.0f - z1)*n1 + z1*hp1;
                hp0 = h0; hp1 = h1v;
                hlds[fb][fj >> 1] = (uint32_t)f2b(h0) | ((uint32_t)f2b(h1v) << 16);
            }
            __syncthreads();

            if (w == 5) {
                const int pb = lane >> 1, ph = lane & 1;
                const uint32_t v0 = hlds[pb][ph*4 + 0];
                const uint32_t v1 = hlds[pb][ph*4 + 1];
                const uint32_t v2 = hlds[pb][ph*4 + 2];
                const uint32_t v3 = hlds[pb][ph*4 + 3];
                uint64_t* dst = (uint64_t*)(hdst + ((size_t)pb*SEQT + t)*HID + j0 + ph*8);
                __hip_atomic_store(dst,   (uint64_t)v0 | ((uint64_t)v1 << 32),
                                   __ATOMIC_RELAXED, __HIP_MEMORY_SCOPE_AGENT);
                __hip_atomic_store(dst+1, (uint64_t)v2 | ((uint64_t)v3 << 32),
                                   __ATOMIC_RELAXED, __HIP_MEMORY_SCOPE_AGENT);
                asm volatile("s_waitcnt vmcnt(0)" ::: "memory");
                if (lane == 0)
                    __hip_atomic_store(myflag, (unsigned)(t+1),
                                       __ATOMIC_RELAXED, __HIP_MEMORY_SCOPE_AGENT);
            }
        }
    }
}

// ---------------------------------------------------------------------------
__global__ __launch_bounds__(256) void diag_kernel(float* __restrict__ out,
                                                   int n, float code)
{
    for (int i = blockIdx.x * 256 + threadIdx.x; i < n; i += gridDim.x * 256)
        out[i] = (i == 0) ? code : 0.0f;
}

// ---------------------------------------------------------------------------
extern "C" void kernel_launch(void* const* d_in, const int* in_sizes, int n_in,
                              void* d_out, int out_size, void* d_ws, size_t ws_size,
                              hipStream_t stream)
{
    const float* x      = (const float*)d_in[0];
    const float* ctx    = (const float*)d_in[1];
    const float* W_in   = (const float*)d_in[2];
    const float* b_in   = (const float*)d_in[3];
    const float* Wih0   = (const float*)d_in[4];
    const float* Whh0   = (const float*)d_in[5];
    const float* bih0   = (const float*)d_in[6];
    const float* bhh0   = (const float*)d_in[7];
    const float* Wih1   = (const float*)d_in[8];
    const float* Whh1   = (const float*)d_in[9];
    const float* bih1   = (const float*)d_in[10];
    const float* bhh1   = (const float*)d_in[11];
    const float* W_out  = (const float*)d_in[12];
    const float* b_out  = (const float*)d_in[13];
    const float* W_gate = (const float*)d_in[14];
    const float* b_gate = (const float*)d_in[15];
    float* out = (float*)d_out;

    // ws layout (~99.2 MB):
    //   mixed [16384][1024] bf16 = 32 MiB
    //   h1    [32][512][1024] bf16 = 32 MiB   (full series)
    //   h2    [32][512][1024] bf16 = 32 MiB
    //   xgs0, xgs1 [64][8][32][48] bf16 = 1.5 MiB each
    //   gate [32][1024] f32 = 128 KiB ; flags 16 KiB
    const size_t MX = (size_t)16384 * 1024 * 2;
    const size_t XS = (size_t)64 * 8 * 32 * 48 * 2;
    const size_t GT = (size_t)32 * 1024 * 4;
    const size_t FL = 16384;
    const size_t need = 3*MX + 2*XS + GT + FL;

    if (ws_size < need) {
        diag_kernel<<<2048, 256, 0, stream>>>(out, out_size, (float)(ws_size >> 20));
        return;
    }

    char* ws = (char*)d_ws;
    unsigned short* mixed = (unsigned short*)ws;
    unsigned short* h1    = (unsigned short*)(ws + MX);
    unsigned short* h2    = (unsigned short*)(ws + 2*MX);
    unsigned short* xgs0  = (unsigned short*)(ws + 3*MX);
    unsigned short* xgs1  = (unsigned short*)(ws + 3*MX + XS);
    float*          gate  = (float*)(ws + 3*MX + 2*XS);
    unsigned int*   flags = (unsigned int*)(ws + 3*MX + 2*XS + GT);

    hipMemsetAsync(flags, 0, FL, stream);
    gate_kernel<<<dim3(4, 32), 256, 0, stream>>>(ctx, W_gate, b_gate, gate);

    // mixed = tanh(x @ W_in^T + b_in + ctx[b]) -> bf16
    mfma_gemm<1, 1, 1><<<dim3(8, 128), 256, 0, stream>>>(
        x, W_in, b_in, ctx, nullptr, mixed, 1024, 1024);

    // 4-stage pipelined GRU section (replaces xg GEMMs + both scans)
    gru_pipe<<<256, 384, 0, stream>>>(
        Wih0, Whh0, bih0, bhh0, Wih1, Whh1, bih1, bhh1,
        mixed, h1, h2, xgs0, xgs1, flags);

    // out = (h2 * (1+gate)) @ W_out^T + b_out -> f32
    mfma_gemm<2, 1, 0><<<dim3(8, 128), 256, 0, stream>>>(
        h2, W_out, b_out, nullptr, gate, out, 1024, 1024);
}